// Round 2
// baseline (718.357 us; speedup 1.0000x reference)
//
#include <hip/hip_runtime.h>
#include <hip/hip_bf16.h>

// DeeperGCN round-1: fp32 I/O (round-0 misread dtypes as bf16 -> half the fp32
// output buffer was never written, absmax == max|ref| exactly).
// Pipeline: edge-layout probe -> CSR build -> encoder GEMV -> [agg -> MLP] x2 -> fused tail.

#define NN 50000
#define EE 800000
#define FIN 128
#define HD 64

__device__ __forceinline__ float wredsum(float v) {
#pragma unroll
    for (int m = 32; m >= 1; m >>= 1) v += __shfl_xor(v, m, 64);
    return v;
}

// ---------------- edge_index layout probe ----------------
// int64 layout: node ids < 2^16 so every odd int32 word is 0.
// int32 layout: odd words are random node ids (P(all 1024 zero) ~ 0).
__global__ void k_detect(const int* __restrict__ ei, int* __restrict__ flag) {
    int i = blockIdx.x * blockDim.x + threadIdx.x;
    if (i < 1024 && ei[2 * i + 1] != 0) atomicExch(flag, 1);  // 1 => int32 layout
}

__device__ __forceinline__ int eidx_src(const int* ei, int e, int is32) {
    return is32 ? ei[e] : ei[2 * e];
}
__device__ __forceinline__ int eidx_dst(const int* ei, int e, int is32) {
    return is32 ? ei[EE + e] : ei[2 * (EE + e)];
}

// ---------------- CSR build ----------------
__global__ void k_hist(const int* __restrict__ ei, const int* __restrict__ flag,
                       int* __restrict__ cnt) {
    int e = blockIdx.x * blockDim.x + threadIdx.x;
    int is32 = *flag;
    if (e < EE) atomicAdd(&cnt[eidx_dst(ei, e, is32)], 1);
}

__global__ __launch_bounds__(1024) void k_scan(const int* __restrict__ cnt,
                                               int* __restrict__ rowptr) {
    __shared__ int ts[1024];
    int t = threadIdx.x;
    const int CH = 49;  // 1024*49 = 50176 >= NN+1
    int base = t * CH;
    int s = 0;
    for (int i = 0; i < CH; i++) {
        int idx = base + i;
        if (idx < NN) s += cnt[idx];
    }
    ts[t] = s;
    __syncthreads();
    for (int d = 1; d < 1024; d <<= 1) {
        int v = (t >= d) ? ts[t - d] : 0;
        __syncthreads();
        ts[t] += v;
        __syncthreads();
    }
    int off = ts[t] - s;  // exclusive prefix
    for (int i = 0; i < CH; i++) {
        int idx = base + i;
        if (idx <= NN) {
            rowptr[idx] = off;
            if (idx < NN) off += cnt[idx];
        }
    }
}

__global__ void k_scatter(const int* __restrict__ ei, const int* __restrict__ flag,
                          const int* __restrict__ rowptr, int* __restrict__ cnt,
                          int* __restrict__ eSrc) {
    int e = blockIdx.x * blockDim.x + threadIdx.x;
    int is32 = *flag;
    if (e < EE) {
        int d = eidx_dst(ei, e, is32);
        int p = atomicAdd(&cnt[d], 1);
        eSrc[rowptr[d] + p] = eidx_src(ei, e, is32);
    }
}

// ---------------- encoder: A[n,c] = x[n,:128] @ encW[:,c] + encB[c] ----------------
// thread = (c in 64, kq in 4); 32 weight regs per thread; 4 nodes per iter.
__global__ __launch_bounds__(256) void k_enc(const float* __restrict__ x,
                                             const float* __restrict__ W,
                                             const float* __restrict__ b,
                                             float* __restrict__ A) {
    __shared__ float4 part[256];
    int t = threadIdx.x;
    int c = t & 63, kq = t >> 6;
    float wr[32];
#pragma unroll
    for (int i = 0; i < 32; i++) wr[i] = W[(kq * 32 + i) * HD + c];
    float bc = b[c];
    for (int n0 = blockIdx.x * 4; n0 < NN; n0 += gridDim.x * 4) {
        float acc[4];
#pragma unroll
        for (int nn = 0; nn < 4; nn++) {
            float a = 0.f;
            int n = n0 + nn;
            if (n < NN) {
                const float4* xr = (const float4*)(x + (size_t)n * FIN + kq * 32);
#pragma unroll
                for (int i = 0; i < 8; i++) {
                    float4 r = xr[i];
                    a += r.x * wr[4 * i] + r.y * wr[4 * i + 1] + r.z * wr[4 * i + 2] +
                         r.w * wr[4 * i + 3];
                }
            }
            acc[nn] = a;
        }
        part[t] = make_float4(acc[0], acc[1], acc[2], acc[3]);
        __syncthreads();
        if (t < 64) {
            float4 s0 = part[t], s1 = part[t + 64], s2 = part[t + 128], s3 = part[t + 192];
            float o[4] = {s0.x + s1.x + s2.x + s3.x + bc, s0.y + s1.y + s2.y + s3.y + bc,
                          s0.z + s1.z + s2.z + s3.z + bc, s0.w + s1.w + s2.w + s3.w + bc};
#pragma unroll
            for (int nn = 0; nn < 4; nn++)
                if (n0 + nn < NN) A[(size_t)(n0 + nn) * HD + c] = o[nn];
        }
        __syncthreads();
    }
}

// ---------------- GENConv softmax aggregation (one wave per node, lane=channel) ----------------
__global__ __launch_bounds__(256) void k_agg(const float* __restrict__ X,
                                             const int* __restrict__ rowptr,
                                             const int* __restrict__ eSrc,
                                             const float* __restrict__ tptr,
                                             float* __restrict__ OUT) {
    int t = threadIdx.x;
    int lane = t & 63, wid = t >> 6;
    float tt = tptr[0];
    for (int n = blockIdx.x * 4 + wid; n < NN; n += gridDim.x * 4) {
        int s = rowptr[n], e = rowptr[n + 1];
        float xv = X[(size_t)n * HD + lane];
        float num = 0.f, den = 0.f;
        for (int i = s; i < e; i++) {
            int sv = eSrc[i];
            float v = X[(size_t)sv * HD + lane];
            float m = fmaxf(v, 0.f) + 1e-7f;
            float p = __expf(m * tt);
            den += p;
            num += m * p;
        }
        float agg = num / (den + 1e-16f);
        OUT[(size_t)n * HD + lane] = agg + xv;
    }
}

// ---------------- fused MLP: relu(LN(in@W1+b1))@W2+b2 ----------------
__global__ __launch_bounds__(256) void k_mlp(const float* __restrict__ IN,
                                             const float* __restrict__ W1,
                                             const float* __restrict__ B1,
                                             const float* __restrict__ G1,
                                             const float* __restrict__ BE1,
                                             const float* __restrict__ W2,
                                             const float* __restrict__ B2,
                                             float* __restrict__ OUT) {
    __shared__ float4 part[256];
    __shared__ float4 redS[2], redQ[2];
    __shared__ float Hl[4 * 128];
    int t = threadIdx.x;
    int j = t & 127, kh = t >> 7;
    int c = t & 63, kq = t >> 6;
    float w1r[32], w2r[32];
#pragma unroll
    for (int i = 0; i < 32; i++) w1r[i] = W1[(kh * 32 + i) * 128 + j];
#pragma unroll
    for (int i = 0; i < 32; i++) w2r[i] = W2[(kq * 32 + i) * 64 + c];
    float b1j = B1[j], g1j = G1[j], bej = BE1[j];
    float b2c = B2[c];

    for (int n0 = blockIdx.x * 4; n0 < NN; n0 += gridDim.x * 4) {
        // stage1: 64 -> 128
        float acc[4];
#pragma unroll
        for (int nn = 0; nn < 4; nn++) {
            float a = 0.f;
            if (n0 + nn < NN) {
                const float4* r4 = (const float4*)(IN + (size_t)(n0 + nn) * HD + kh * 32);
#pragma unroll
                for (int i = 0; i < 8; i++) {
                    float4 r = r4[i];
                    a += r.x * w1r[4 * i] + r.y * w1r[4 * i + 1] + r.z * w1r[4 * i + 2] +
                         r.w * w1r[4 * i + 3];
                }
            }
            acc[nn] = a;
        }
        part[t] = make_float4(acc[0], acc[1], acc[2], acc[3]);
        __syncthreads();
        float vv[4];
        if (t < 128) {
            float4 v = part[t], v2 = part[t + 128];
            vv[0] = v.x + v2.x + b1j;
            vv[1] = v.y + v2.y + b1j;
            vv[2] = v.z + v2.z + b1j;
            vv[3] = v.w + v2.w + b1j;
            float sv[4], qv[4];
#pragma unroll
            for (int nn = 0; nn < 4; nn++) {
                sv[nn] = vv[nn];
                qv[nn] = vv[nn] * vv[nn];
            }
#pragma unroll
            for (int m = 32; m >= 1; m >>= 1) {
#pragma unroll
                for (int nn = 0; nn < 4; nn++) {
                    sv[nn] += __shfl_xor(sv[nn], m, 64);
                    qv[nn] += __shfl_xor(qv[nn], m, 64);
                }
            }
            if ((t & 63) == 0) {
                redS[t >> 6] = make_float4(sv[0], sv[1], sv[2], sv[3]);
                redQ[t >> 6] = make_float4(qv[0], qv[1], qv[2], qv[3]);
            }
        }
        __syncthreads();
        if (t < 128) {
            float S[4] = {redS[0].x + redS[1].x, redS[0].y + redS[1].y, redS[0].z + redS[1].z,
                          redS[0].w + redS[1].w};
            float Q[4] = {redQ[0].x + redQ[1].x, redQ[0].y + redQ[1].y, redQ[0].z + redQ[1].z,
                          redQ[0].w + redQ[1].w};
#pragma unroll
            for (int nn = 0; nn < 4; nn++) {
                float mu = S[nn] * (1.f / 128.f);
                float var = Q[nn] * (1.f / 128.f) - mu * mu;
                float h = (vv[nn] - mu) * rsqrtf(var + 1e-5f) * g1j + bej;
                Hl[nn * 128 + j] = fmaxf(h, 0.f);
            }
        }
        __syncthreads();
        // stage2: 128 -> 64
        float acc2[4];
#pragma unroll
        for (int nn = 0; nn < 4; nn++) {
            float a = 0.f;
            const float4* h4 = (const float4*)(Hl + nn * 128 + kq * 32);
#pragma unroll
            for (int i = 0; i < 8; i++) {
                float4 h = h4[i];
                a += h.x * w2r[4 * i] + h.y * w2r[4 * i + 1] + h.z * w2r[4 * i + 2] +
                     h.w * w2r[4 * i + 3];
            }
            acc2[nn] = a;
        }
        __syncthreads();
        part[t] = make_float4(acc2[0], acc2[1], acc2[2], acc2[3]);
        __syncthreads();
        if (t < 64) {
            float4 a0 = part[t], a1 = part[t + 64], a2 = part[t + 128], a3 = part[t + 192];
            float o[4] = {a0.x + a1.x + a2.x + a3.x + b2c, a0.y + a1.y + a2.y + a3.y + b2c,
                          a0.z + a1.z + a2.z + a3.z + b2c, a0.w + a1.w + a2.w + a3.w + b2c};
#pragma unroll
            for (int nn = 0; nn < 4; nn++)
                if (n0 + nn < NN) OUT[(size_t)(n0 + nn) * HD + t] = o[nn];
        }
        __syncthreads();
    }
}

// ---------------- fused tail: relu(LN64(h2)); relu(LN128(cat(x1,hn))); @lin_W + lin_b ----------------
__global__ __launch_bounds__(256) void k_final(const float* __restrict__ X1,
                                               const float* __restrict__ H2,
                                               const float* __restrict__ LG,
                                               const float* __restrict__ LB,
                                               const float* __restrict__ NG,
                                               const float* __restrict__ NB_,
                                               const float* __restrict__ LW,
                                               const float* __restrict__ LBias,
                                               float* __restrict__ out) {
    int t = threadIdx.x;
    int lane = t & 63, wid = t >> 6;
    int n = blockIdx.x * 4 + wid;
    if (n >= NN) return;
    float x1v = X1[(size_t)n * HD + lane];
    float h2v = H2[(size_t)n * HD + lane];
    float s = wredsum(h2v);
    float q = wredsum(h2v * h2v);
    float mu = s * (1.f / 64.f);
    float var = q * (1.f / 64.f) - mu * mu;
    float hn = (h2v - mu) * rsqrtf(var + 1e-5f) * LG[lane] + LB[lane];
    hn = fmaxf(hn, 0.f);
    float s2 = wredsum(x1v + hn);
    float q2 = wredsum(x1v * x1v + hn * hn);
    float mu2 = s2 * (1.f / 128.f);
    float var2 = q2 * (1.f / 128.f) - mu2 * mu2;
    float rs2 = rsqrtf(var2 + 1e-5f);
    float av = fmaxf((x1v - mu2) * rs2 * NG[lane] + NB_[lane], 0.f);
    float bv = fmaxf((hn - mu2) * rs2 * NG[64 + lane] + NB_[64 + lane], 0.f);
    float acc = av * LW[lane] + bv * LW[64 + lane];
    float tot = wredsum(acc);
    if (lane == 0) out[n] = tot + LBias[0];
}

extern "C" void kernel_launch(void* const* d_in, const int* in_sizes, int n_in,
                              void* d_out, int out_size, void* d_ws, size_t ws_size,
                              hipStream_t stream) {
    const float* x = (const float*)d_in[0];
    const int* ei = (const int*)d_in[1];
    const float* encW = (const float*)d_in[2];
    const float* encB = (const float*)d_in[3];
    const float* tptr = (const float*)d_in[4];
    const float* cW1 = (const float*)d_in[5];
    const float* cB1 = (const float*)d_in[6];
    const float* cG1 = (const float*)d_in[7];
    const float* cBE1 = (const float*)d_in[8];
    const float* cW2 = (const float*)d_in[9];
    const float* cB2 = (const float*)d_in[10];
    const float* ln1g = (const float*)d_in[11];
    const float* ln1b = (const float*)d_in[12];
    const float* ng = (const float*)d_in[13];
    const float* nb = (const float*)d_in[14];
    const float* lw = (const float*)d_in[15];
    const float* lb = (const float*)d_in[16];

    char* w = (char*)d_ws;
    size_t off = 0;
    auto carve = [&](size_t bytes) {
        void* p = w + off;
        off += (bytes + 255) & ~(size_t)255;
        return p;
    };
    int* flag = (int*)carve(4);
    int* rowptr = (int*)carve((NN + 1) * 4);
    int* cnt = (int*)carve((size_t)NN * 4);
    int* eSrc = (int*)carve((size_t)EE * 4);
    float* A = (float*)carve((size_t)NN * HD * 4);
    float* AG = (float*)carve((size_t)NN * HD * 4);
    float* X1 = (float*)carve((size_t)NN * HD * 4);
    float* H2 = A;  // A dead after conv1 aggregation; reuse for conv2 output

    hipMemsetAsync(flag, 0, 4, stream);
    hipMemsetAsync(cnt, 0, (size_t)NN * 4, stream);
    k_detect<<<4, 256, 0, stream>>>(ei, flag);
    k_hist<<<(EE + 255) / 256, 256, 0, stream>>>(ei, flag, cnt);
    k_scan<<<1, 1024, 0, stream>>>(cnt, rowptr);
    hipMemsetAsync(cnt, 0, (size_t)NN * 4, stream);
    k_scatter<<<(EE + 255) / 256, 256, 0, stream>>>(ei, flag, rowptr, cnt, eSrc);

    k_enc<<<1024, 256, 0, stream>>>(x, encW, encB, A);

    // conv1
    k_agg<<<2048, 256, 0, stream>>>(A, rowptr, eSrc, tptr, AG);
    k_mlp<<<2048, 256, 0, stream>>>(AG, cW1, cB1, cG1, cBE1, cW2, cB2, X1);
    // conv2 (shared weights)
    k_agg<<<2048, 256, 0, stream>>>(X1, rowptr, eSrc, tptr, AG);
    k_mlp<<<2048, 256, 0, stream>>>(AG, cW1, cB1, cG1, cBE1, cW2, cB2, H2);

    k_final<<<(NN + 3) / 4, 256, 0, stream>>>(X1, H2, ln1g, ln1b, ng, nb, lw, lb,
                                              (float*)d_out);
}

// Round 3
// 500.988 us; speedup vs baseline: 1.4339x; 1.4339x over previous
//
#include <hip/hip_runtime.h>
#include <hip/hip_bf16.h>

// DeeperGCN round-2: MFMA bf16 for all GEMMs (enc + 2x MLP), bf16 gather in agg.
// Verified MFMA layouts (learn_hip m89/m120): C/D col=lane&15,row=(lane>>4)*4+reg;
// A[m=lane&15][k=(lane>>4)*8+j]; B[k=(lane>>4)*8+j][n=lane&15].
// Residual/concat path (X1) kept fp32 for the final LN; everything else bf16.

#define NN 50000
#define EE 800000
#define FIN 128
#define HD 64

typedef unsigned short u16;
typedef unsigned int u32;
using bf16x8 = __attribute__((ext_vector_type(8))) short;
using f32x4 = __attribute__((ext_vector_type(4))) float;

__device__ __forceinline__ float bf2f(u16 u) {
    u32 x = ((u32)u) << 16;
    float f;
    __builtin_memcpy(&f, &x, 4);
    return f;
}
__device__ __forceinline__ short f2bf(float f) {
    u32 u;
    __builtin_memcpy(&u, &f, 4);
    u32 r = (u + 0x7fffu + ((u >> 16) & 1u)) >> 16;  // RNE
    return (short)r;
}
__device__ __forceinline__ float wredsum(float v) {
#pragma unroll
    for (int m = 32; m >= 1; m >>= 1) v += __shfl_xor(v, m, 64);
    return v;
}

// ---------------- edge_index layout probe (int64 vs int32 words) ----------------
__global__ void k_detect(const int* __restrict__ ei, int* __restrict__ flag) {
    int i = blockIdx.x * blockDim.x + threadIdx.x;
    if (i < 1024 && ei[2 * i + 1] != 0) atomicExch(flag, 1);  // 1 => int32 layout
}
__device__ __forceinline__ int eidx_src(const int* ei, int e, int is32) {
    return is32 ? ei[e] : ei[2 * e];
}
__device__ __forceinline__ int eidx_dst(const int* ei, int e, int is32) {
    return is32 ? ei[EE + e] : ei[2 * (EE + e)];
}

// ---------------- CSR build ----------------
__global__ void k_hist(const int* __restrict__ ei, const int* __restrict__ flag,
                       int* __restrict__ cnt) {
    int e = blockIdx.x * blockDim.x + threadIdx.x;
    int is32 = *flag;
    if (e < EE) atomicAdd(&cnt[eidx_dst(ei, e, is32)], 1);
}

__global__ __launch_bounds__(1024) void k_scan(const int* __restrict__ cnt,
                                               int* __restrict__ rowptr) {
    __shared__ int ts[1024];
    int t = threadIdx.x;
    const int CH = 49;
    int base = t * CH;
    int s = 0;
    for (int i = 0; i < CH; i++) {
        int idx = base + i;
        if (idx < NN) s += cnt[idx];
    }
    ts[t] = s;
    __syncthreads();
    for (int d = 1; d < 1024; d <<= 1) {
        int v = (t >= d) ? ts[t - d] : 0;
        __syncthreads();
        ts[t] += v;
        __syncthreads();
    }
    int off = ts[t] - s;
    for (int i = 0; i < CH; i++) {
        int idx = base + i;
        if (idx <= NN) {
            rowptr[idx] = off;
            if (idx < NN) off += cnt[idx];
        }
    }
}

__global__ void k_scatter(const int* __restrict__ ei, const int* __restrict__ flag,
                          const int* __restrict__ rowptr, int* __restrict__ cnt,
                          int* __restrict__ eSrc) {
    int e = blockIdx.x * blockDim.x + threadIdx.x;
    int is32 = *flag;
    if (e < EE) {
        int d = eidx_dst(ei, e, is32);
        int p = atomicAdd(&cnt[d], 1);
        eSrc[rowptr[d] + p] = eidx_src(ei, e, is32);
    }
}

// ---------------- encoder (MFMA): Abf[n,0:64] = bf16(x[n,0:128] @ encW + encB) ----------------
__global__ __launch_bounds__(256) void k_enc(const float* __restrict__ x,
                                             const float* __restrict__ W,
                                             const float* __restrict__ b,
                                             u16* __restrict__ Abf) {
    __shared__ short wtE[64 * 136];  // WT[n][k], k padded 128->136 (bank stagger)
    int tid = threadIdx.x;
    for (int i = tid; i < FIN * HD; i += 256) wtE[(i & 63) * 136 + (i >> 6)] = f2bf(W[i]);
    __syncthreads();

    int lane = tid & 63, wid = tid >> 6;
    int l16 = lane & 15, q = lane >> 4;
    int m0 = blockIdx.x * 64 + wid * 16;
    int mrow = m0 + l16;
    if (mrow >= NN) mrow = NN - 1;

    // A-frags from x (fp32 -> bf16), K=128 in 4 chunks of 32
    bf16x8 af[4];
#pragma unroll
    for (int c = 0; c < 4; c++) {
        const float4* p = (const float4*)(x + (size_t)mrow * FIN + c * 32 + q * 8);
        float4 p0 = p[0], p1 = p[1];
        af[c][0] = f2bf(p0.x); af[c][1] = f2bf(p0.y); af[c][2] = f2bf(p0.z); af[c][3] = f2bf(p0.w);
        af[c][4] = f2bf(p1.x); af[c][5] = f2bf(p1.y); af[c][6] = f2bf(p1.z); af[c][7] = f2bf(p1.w);
    }
    f32x4 acc[4];
#pragma unroll
    for (int u = 0; u < 4; u++) {
        f32x4 z = {0.f, 0.f, 0.f, 0.f};
#pragma unroll
        for (int c = 0; c < 4; c++) {
            bf16x8 wf = *(const bf16x8*)(const void*)&wtE[(u * 16 + l16) * 136 + c * 32 + q * 8];
            z = __builtin_amdgcn_mfma_f32_16x16x32_bf16(af[c], wf, z, 0, 0, 0);
        }
        acc[u] = z;
    }
#pragma unroll
    for (int u = 0; u < 4; u++) {
        int col = u * 16 + l16;
        float bc = b[col];
#pragma unroll
        for (int r = 0; r < 4; r++) {
            int node = m0 + q * 4 + r;
            if (node < NN) Abf[(size_t)node * HD + col] = (u16)f2bf(acc[u][r] + bc);
        }
    }
}

// ---------------- GENConv softmax aggregation (bf16 gather, lane=channel) ----------------
__global__ __launch_bounds__(256) void k_agg(const u16* __restrict__ Xbf,
                                             const float* __restrict__ Xfp,  // self (may be null)
                                             const int* __restrict__ rowptr,
                                             const int* __restrict__ eSrc,
                                             const float* __restrict__ tptr,
                                             u16* __restrict__ OUTbf) {
    int t = threadIdx.x;
    int lane = t & 63, wid = t >> 6;
    float tt = tptr[0];
    for (int n = blockIdx.x * 4 + wid; n < NN; n += gridDim.x * 4) {
        int s = rowptr[n], e = rowptr[n + 1];
        float xv = Xfp ? Xfp[(size_t)n * HD + lane] : bf2f(Xbf[(size_t)n * HD + lane]);
        float num = 0.f, den = 0.f;
        for (int i = s; i < e; i++) {
            int sv = eSrc[i];
            float v = bf2f(Xbf[(size_t)sv * HD + lane]);
            float m = fmaxf(v, 0.f) + 1e-7f;
            float p = __expf(m * tt);
            den += p;
            num += m * p;
        }
        float agg = num / (den + 1e-16f);
        OUTbf[(size_t)n * HD + lane] = (u16)f2bf(agg + xv);
    }
}

// ---------------- fused MLP (MFMA): relu(LN(in@W1+b1))@W2+b2 ----------------
__global__ __launch_bounds__(256) void k_mlp(const u16* __restrict__ INbf,
                                             const float* __restrict__ W1,
                                             const float* __restrict__ B1,
                                             const float* __restrict__ G1,
                                             const float* __restrict__ BE1,
                                             const float* __restrict__ W2,
                                             const float* __restrict__ B2,
                                             float* __restrict__ OUTfp,  // may be null
                                             u16* __restrict__ OUTbf) {
    __shared__ short wt1[128 * 72];      // W1T[j][k], k 64->72
    __shared__ short wt2[64 * 136];      // W2T[c][k], k 128->136
    __shared__ short hbuf[64 * 136];     // per-wave 16x128 H, row pad 136
    int tid = threadIdx.x;
    for (int i = tid; i < HD * 128; i += 256) wt1[(i & 127) * 72 + (i >> 7)] = f2bf(W1[i]);
    for (int i = tid; i < 128 * HD; i += 256) wt2[(i & 63) * 136 + (i >> 6)] = f2bf(W2[i]);
    __syncthreads();

    int lane = tid & 63, wid = tid >> 6;
    int l16 = lane & 15, q = lane >> 4;
    int m0 = blockIdx.x * 64 + wid * 16;
    int mrow = m0 + l16;
    if (mrow >= NN) mrow = NN - 1;

    // per-lane column params for stage1 (j = tl*16 + l16)
    float b1v[8], g1v[8], bev[8];
#pragma unroll
    for (int tl = 0; tl < 8; tl++) {
        int j = tl * 16 + l16;
        b1v[tl] = B1[j];
        g1v[tl] = G1[j];
        bev[tl] = BE1[j];
    }

    // GEMM1: [16x64] @ [64x128]
    bf16x8 a0 = *(const bf16x8*)(const void*)(INbf + (size_t)mrow * HD + q * 8);
    bf16x8 a1 = *(const bf16x8*)(const void*)(INbf + (size_t)mrow * HD + 32 + q * 8);
    f32x4 acc1[8];
#pragma unroll
    for (int tl = 0; tl < 8; tl++) {
        bf16x8 w0 = *(const bf16x8*)(const void*)&wt1[(tl * 16 + l16) * 72 + q * 8];
        bf16x8 w1 = *(const bf16x8*)(const void*)&wt1[(tl * 16 + l16) * 72 + 32 + q * 8];
        f32x4 z = {0.f, 0.f, 0.f, 0.f};
        z = __builtin_amdgcn_mfma_f32_16x16x32_bf16(a0, w0, z, 0, 0, 0);
        z = __builtin_amdgcn_mfma_f32_16x16x32_bf16(a1, w1, z, 0, 0, 0);
        acc1[tl] = z;
    }
    // bias + LN(128) + relu; row r's 128 j-values live in this quad's 16 lanes x 8 tiles
    float S[4] = {0, 0, 0, 0}, Q[4] = {0, 0, 0, 0};
#pragma unroll
    for (int tl = 0; tl < 8; tl++)
#pragma unroll
        for (int r = 0; r < 4; r++) {
            float v = acc1[tl][r] + b1v[tl];
            acc1[tl][r] = v;
            S[r] += v;
            Q[r] += v * v;
        }
#pragma unroll
    for (int m = 8; m >= 1; m >>= 1)
#pragma unroll
        for (int r = 0; r < 4; r++) {
            S[r] += __shfl_xor(S[r], m, 64);
            Q[r] += __shfl_xor(Q[r], m, 64);
        }
    float mu[4], rs[4];
#pragma unroll
    for (int r = 0; r < 4; r++) {
        mu[r] = S[r] * (1.f / 128.f);
        float var = Q[r] * (1.f / 128.f) - mu[r] * mu[r];
        rs[r] = rsqrtf(var + 1e-5f);
    }
#pragma unroll
    for (int tl = 0; tl < 8; tl++)
#pragma unroll
        for (int r = 0; r < 4; r++) {
            float h = fmaxf((acc1[tl][r] - mu[r]) * rs[r] * g1v[tl] + bev[tl], 0.f);
            hbuf[(wid * 16 + q * 4 + r) * 136 + tl * 16 + l16] = f2bf(h);
        }
    // wave-private LDS region: no barrier needed (compiler orders via lgkmcnt)

    // GEMM2: [16x128] @ [128x64]
    bf16x8 a2[4];
#pragma unroll
    for (int c = 0; c < 4; c++)
        a2[c] = *(const bf16x8*)(const void*)&hbuf[(wid * 16 + l16) * 136 + c * 32 + q * 8];
    f32x4 acc2[4];
#pragma unroll
    for (int u = 0; u < 4; u++) {
        f32x4 z = {0.f, 0.f, 0.f, 0.f};
#pragma unroll
        for (int c = 0; c < 4; c++) {
            bf16x8 wf = *(const bf16x8*)(const void*)&wt2[(u * 16 + l16) * 136 + c * 32 + q * 8];
            z = __builtin_amdgcn_mfma_f32_16x16x32_bf16(a2[c], wf, z, 0, 0, 0);
        }
        acc2[u] = z;
    }
#pragma unroll
    for (int u = 0; u < 4; u++) {
        int col = u * 16 + l16;
        float bc = B2[col];
#pragma unroll
        for (int r = 0; r < 4; r++) {
            int node = m0 + q * 4 + r;
            if (node < NN) {
                float val = acc2[u][r] + bc;
                if (OUTfp) OUTfp[(size_t)node * HD + col] = val;
                OUTbf[(size_t)node * HD + col] = (u16)f2bf(val);
            }
        }
    }
}

// ---------------- fused tail ----------------
__global__ __launch_bounds__(256) void k_final(const float* __restrict__ X1,
                                               const u16* __restrict__ H2bf,
                                               const float* __restrict__ LG,
                                               const float* __restrict__ LB,
                                               const float* __restrict__ NG,
                                               const float* __restrict__ NB_,
                                               const float* __restrict__ LW,
                                               const float* __restrict__ LBias,
                                               float* __restrict__ out) {
    int t = threadIdx.x;
    int lane = t & 63, wid = t >> 6;
    int n = blockIdx.x * 4 + wid;
    if (n >= NN) return;
    float x1v = X1[(size_t)n * HD + lane];
    float h2v = bf2f(H2bf[(size_t)n * HD + lane]);
    float s = wredsum(h2v);
    float qq = wredsum(h2v * h2v);
    float mu = s * (1.f / 64.f);
    float var = qq * (1.f / 64.f) - mu * mu;
    float hn = fmaxf((h2v - mu) * rsqrtf(var + 1e-5f) * LG[lane] + LB[lane], 0.f);
    float s2 = wredsum(x1v + hn);
    float q2 = wredsum(x1v * x1v + hn * hn);
    float mu2 = s2 * (1.f / 128.f);
    float var2 = q2 * (1.f / 128.f) - mu2 * mu2;
    float rs2 = rsqrtf(var2 + 1e-5f);
    float av = fmaxf((x1v - mu2) * rs2 * NG[lane] + NB_[lane], 0.f);
    float bv = fmaxf((hn - mu2) * rs2 * NG[64 + lane] + NB_[64 + lane], 0.f);
    float acc = av * LW[lane] + bv * LW[64 + lane];
    float tot = wredsum(acc);
    if (lane == 0) out[n] = tot + LBias[0];
}

extern "C" void kernel_launch(void* const* d_in, const int* in_sizes, int n_in,
                              void* d_out, int out_size, void* d_ws, size_t ws_size,
                              hipStream_t stream) {
    const float* x = (const float*)d_in[0];
    const int* ei = (const int*)d_in[1];
    const float* encW = (const float*)d_in[2];
    const float* encB = (const float*)d_in[3];
    const float* tptr = (const float*)d_in[4];
    const float* cW1 = (const float*)d_in[5];
    const float* cB1 = (const float*)d_in[6];
    const float* cG1 = (const float*)d_in[7];
    const float* cBE1 = (const float*)d_in[8];
    const float* cW2 = (const float*)d_in[9];
    const float* cB2 = (const float*)d_in[10];
    const float* ln1g = (const float*)d_in[11];
    const float* ln1b = (const float*)d_in[12];
    const float* ng = (const float*)d_in[13];
    const float* nb = (const float*)d_in[14];
    const float* lw = (const float*)d_in[15];
    const float* lb = (const float*)d_in[16];

    char* w = (char*)d_ws;
    size_t off = 0;
    auto carve = [&](size_t bytes) {
        void* p = w + off;
        off += (bytes + 255) & ~(size_t)255;
        return p;
    };
    int* flag = (int*)carve(4);
    int* rowptr = (int*)carve((NN + 1) * 4);
    int* cnt = (int*)carve((size_t)NN * 4);
    int* eSrc = (int*)carve((size_t)EE * 4);
    u16* Abf = (u16*)carve((size_t)NN * HD * 2);
    u16* AGbf = (u16*)carve((size_t)NN * HD * 2);
    float* X1 = (float*)carve((size_t)NN * HD * 4);
    u16* X1bf = (u16*)carve((size_t)NN * HD * 2);
    u16* H2bf = Abf;  // Abf dead after agg1

    hipMemsetAsync(flag, 0, 4, stream);
    hipMemsetAsync(cnt, 0, (size_t)NN * 4, stream);
    k_detect<<<4, 256, 0, stream>>>(ei, flag);
    k_hist<<<(EE + 255) / 256, 256, 0, stream>>>(ei, flag, cnt);
    k_scan<<<1, 1024, 0, stream>>>(cnt, rowptr);
    hipMemsetAsync(cnt, 0, (size_t)NN * 4, stream);
    k_scatter<<<(EE + 255) / 256, 256, 0, stream>>>(ei, flag, rowptr, cnt, eSrc);

    const int GB = (NN + 63) / 64;  // 782
    k_enc<<<GB, 256, 0, stream>>>(x, encW, encB, Abf);

    // conv1
    k_agg<<<2048, 256, 0, stream>>>(Abf, nullptr, rowptr, eSrc, tptr, AGbf);
    k_mlp<<<GB, 256, 0, stream>>>(AGbf, cW1, cB1, cG1, cBE1, cW2, cB2, X1, X1bf);
    // conv2 (shared weights)
    k_agg<<<2048, 256, 0, stream>>>(X1bf, X1, rowptr, eSrc, tptr, AGbf);
    k_mlp<<<GB, 256, 0, stream>>>(AGbf, cW1, cB1, cG1, cBE1, cW2, cB2, nullptr, H2bf);

    k_final<<<(NN + 3) / 4, 256, 0, stream>>>(X1, H2bf, ln1g, ln1b, ng, nb, lw, lb,
                                              (float*)d_out);
}

// Round 4
// 328.543 us; speedup vs baseline: 2.1865x; 1.5249x over previous
//
#include <hip/hip_runtime.h>
#include <hip/hip_bf16.h>

// DeeperGCN round-3: replace single-block k_scan (96us, 0.16% occupancy) with
// two-level multi-block scan (~12us); unroll k_agg edge loop x8 for MLP latency
// hiding. MFMA GEMMs unchanged from round-2.

#define NN 50000
#define EE 800000
#define FIN 128
#define HD 64
#define NB 196  // scan blocks: 196*256 = 50176 >= NN+1

typedef unsigned short u16;
typedef unsigned int u32;
using bf16x8 = __attribute__((ext_vector_type(8))) short;
using f32x4 = __attribute__((ext_vector_type(4))) float;

__device__ __forceinline__ float bf2f(u16 u) {
    u32 x = ((u32)u) << 16;
    float f;
    __builtin_memcpy(&f, &x, 4);
    return f;
}
__device__ __forceinline__ short f2bf(float f) {
    u32 u;
    __builtin_memcpy(&u, &f, 4);
    u32 r = (u + 0x7fffu + ((u >> 16) & 1u)) >> 16;  // RNE
    return (short)r;
}
__device__ __forceinline__ float wredsum(float v) {
#pragma unroll
    for (int m = 32; m >= 1; m >>= 1) v += __shfl_xor(v, m, 64);
    return v;
}

// ---------------- edge_index layout probe (int64 vs int32 words) ----------------
__global__ void k_detect(const int* __restrict__ ei, int* __restrict__ flag) {
    int i = blockIdx.x * blockDim.x + threadIdx.x;
    if (i < 1024 && ei[2 * i + 1] != 0) atomicExch(flag, 1);  // 1 => int32 layout
}
__device__ __forceinline__ int eidx_src(const int* ei, int e, int is32) {
    return is32 ? ei[e] : ei[2 * e];
}
__device__ __forceinline__ int eidx_dst(const int* ei, int e, int is32) {
    return is32 ? ei[EE + e] : ei[2 * (EE + e)];
}

// ---------------- CSR build ----------------
__global__ void k_hist(const int* __restrict__ ei, const int* __restrict__ flag,
                       int* __restrict__ cnt) {
    int e = blockIdx.x * blockDim.x + threadIdx.x;
    int is32 = *flag;
    if (e < EE) atomicAdd(&cnt[eidx_dst(ei, e, is32)], 1);
}

// two-level scan: per-block exclusive scan + block sums
__global__ __launch_bounds__(256) void k_scan1(const int* __restrict__ cnt,
                                               int* __restrict__ rowptr,
                                               int* __restrict__ bsum) {
    __shared__ int ts[256];
    int t = threadIdx.x;
    int idx = blockIdx.x * 256 + t;
    int v = (idx < NN) ? cnt[idx] : 0;
    ts[t] = v;
    __syncthreads();
#pragma unroll
    for (int d = 1; d < 256; d <<= 1) {
        int u = (t >= d) ? ts[t - d] : 0;
        __syncthreads();
        ts[t] += u;
        __syncthreads();
    }
    if (idx <= NN) rowptr[idx] = ts[t] - v;  // local exclusive prefix
    if (t == 255) bsum[blockIdx.x] = ts[255];
}

__global__ __launch_bounds__(256) void k_scan2(int* __restrict__ bsum) {
    __shared__ int ts[256];
    int t = threadIdx.x;
    int v = (t < NB) ? bsum[t] : 0;
    ts[t] = v;
    __syncthreads();
#pragma unroll
    for (int d = 1; d < 256; d <<= 1) {
        int u = (t >= d) ? ts[t - d] : 0;
        __syncthreads();
        ts[t] += u;
        __syncthreads();
    }
    if (t < NB) bsum[t] = ts[t] - v;  // exclusive block offsets
}

// add block offsets; also re-zero cnt for the scatter pass (saves a memset)
__global__ __launch_bounds__(256) void k_scan3(const int* __restrict__ bsum,
                                               int* __restrict__ rowptr,
                                               int* __restrict__ cnt) {
    int idx = blockIdx.x * 256 + threadIdx.x;
    if (idx <= NN) rowptr[idx] += bsum[blockIdx.x];
    if (idx < NN) cnt[idx] = 0;
}

__global__ void k_scatter(const int* __restrict__ ei, const int* __restrict__ flag,
                          const int* __restrict__ rowptr, int* __restrict__ cnt,
                          int* __restrict__ eSrc) {
    int e = blockIdx.x * blockDim.x + threadIdx.x;
    int is32 = *flag;
    if (e < EE) {
        int d = eidx_dst(ei, e, is32);
        int p = atomicAdd(&cnt[d], 1);
        eSrc[rowptr[d] + p] = eidx_src(ei, e, is32);
    }
}

// ---------------- encoder (MFMA): Abf[n,0:64] = bf16(x[n,0:128] @ encW + encB) ----------------
__global__ __launch_bounds__(256) void k_enc(const float* __restrict__ x,
                                             const float* __restrict__ W,
                                             const float* __restrict__ b,
                                             u16* __restrict__ Abf) {
    __shared__ short wtE[64 * 136];  // WT[n][k], k padded 128->136
    int tid = threadIdx.x;
    for (int i = tid; i < FIN * HD; i += 256) wtE[(i & 63) * 136 + (i >> 6)] = f2bf(W[i]);
    __syncthreads();

    int lane = tid & 63, wid = tid >> 6;
    int l16 = lane & 15, q = lane >> 4;
    int m0 = blockIdx.x * 64 + wid * 16;
    int mrow = m0 + l16;
    if (mrow >= NN) mrow = NN - 1;

    bf16x8 af[4];
#pragma unroll
    for (int c = 0; c < 4; c++) {
        const float4* p = (const float4*)(x + (size_t)mrow * FIN + c * 32 + q * 8);
        float4 p0 = p[0], p1 = p[1];
        af[c][0] = f2bf(p0.x); af[c][1] = f2bf(p0.y); af[c][2] = f2bf(p0.z); af[c][3] = f2bf(p0.w);
        af[c][4] = f2bf(p1.x); af[c][5] = f2bf(p1.y); af[c][6] = f2bf(p1.z); af[c][7] = f2bf(p1.w);
    }
    f32x4 acc[4];
#pragma unroll
    for (int u = 0; u < 4; u++) {
        f32x4 z = {0.f, 0.f, 0.f, 0.f};
#pragma unroll
        for (int c = 0; c < 4; c++) {
            bf16x8 wf = *(const bf16x8*)(const void*)&wtE[(u * 16 + l16) * 136 + c * 32 + q * 8];
            z = __builtin_amdgcn_mfma_f32_16x16x32_bf16(af[c], wf, z, 0, 0, 0);
        }
        acc[u] = z;
    }
#pragma unroll
    for (int u = 0; u < 4; u++) {
        int col = u * 16 + l16;
        float bc = b[col];
#pragma unroll
        for (int r = 0; r < 4; r++) {
            int node = m0 + q * 4 + r;
            if (node < NN) Abf[(size_t)node * HD + col] = (u16)f2bf(acc[u][r] + bc);
        }
    }
}

// ---------------- GENConv softmax aggregation (bf16 gather, lane=channel, unroll x8) --------
__global__ __launch_bounds__(256) void k_agg(const u16* __restrict__ Xbf,
                                             const float* __restrict__ Xfp,  // self (may be null)
                                             const int* __restrict__ rowptr,
                                             const int* __restrict__ eSrc,
                                             const float* __restrict__ tptr,
                                             u16* __restrict__ OUTbf) {
    int t = threadIdx.x;
    int lane = t & 63, wid = t >> 6;
    float tt = tptr[0];
    for (int n = blockIdx.x * 4 + wid; n < NN; n += gridDim.x * 4) {
        int s = rowptr[n], e = rowptr[n + 1];
        float xv = Xfp ? Xfp[(size_t)n * HD + lane] : bf2f(Xbf[(size_t)n * HD + lane]);
        float num = 0.f, den = 0.f;
        int i = s;
        for (; i + 7 < e; i += 8) {
            int sv[8];
#pragma unroll
            for (int k = 0; k < 8; k++) sv[k] = eSrc[i + k];
            float v[8];
#pragma unroll
            for (int k = 0; k < 8; k++) v[k] = bf2f(Xbf[(size_t)sv[k] * HD + lane]);
#pragma unroll
            for (int k = 0; k < 8; k++) {
                float m = fmaxf(v[k], 0.f) + 1e-7f;
                float p = __expf(m * tt);
                den += p;
                num += m * p;
            }
        }
        for (; i < e; i++) {
            float v = bf2f(Xbf[(size_t)eSrc[i] * HD + lane]);
            float m = fmaxf(v, 0.f) + 1e-7f;
            float p = __expf(m * tt);
            den += p;
            num += m * p;
        }
        float agg = num / (den + 1e-16f);
        OUTbf[(size_t)n * HD + lane] = (u16)f2bf(agg + xv);
    }
}

// ---------------- fused MLP (MFMA): relu(LN(in@W1+b1))@W2+b2 ----------------
__global__ __launch_bounds__(256) void k_mlp(const u16* __restrict__ INbf,
                                             const float* __restrict__ W1,
                                             const float* __restrict__ B1,
                                             const float* __restrict__ G1,
                                             const float* __restrict__ BE1,
                                             const float* __restrict__ W2,
                                             const float* __restrict__ B2,
                                             float* __restrict__ OUTfp,  // may be null
                                             u16* __restrict__ OUTbf) {
    __shared__ short wt1[128 * 72];   // W1T[j][k], k 64->72
    __shared__ short wt2[64 * 136];   // W2T[c][k], k 128->136
    __shared__ short hbuf[64 * 136];  // per-wave 16x128 H, row pad 136
    int tid = threadIdx.x;
    for (int i = tid; i < HD * 128; i += 256) wt1[(i & 127) * 72 + (i >> 7)] = f2bf(W1[i]);
    for (int i = tid; i < 128 * HD; i += 256) wt2[(i & 63) * 136 + (i >> 6)] = f2bf(W2[i]);
    __syncthreads();

    int lane = tid & 63, wid = tid >> 6;
    int l16 = lane & 15, q = lane >> 4;
    int m0 = blockIdx.x * 64 + wid * 16;
    int mrow = m0 + l16;
    if (mrow >= NN) mrow = NN - 1;

    float b1v[8], g1v[8], bev[8];
#pragma unroll
    for (int tl = 0; tl < 8; tl++) {
        int j = tl * 16 + l16;
        b1v[tl] = B1[j];
        g1v[tl] = G1[j];
        bev[tl] = BE1[j];
    }

    // GEMM1: [16x64] @ [64x128]
    bf16x8 a0 = *(const bf16x8*)(const void*)(INbf + (size_t)mrow * HD + q * 8);
    bf16x8 a1 = *(const bf16x8*)(const void*)(INbf + (size_t)mrow * HD + 32 + q * 8);
    f32x4 acc1[8];
#pragma unroll
    for (int tl = 0; tl < 8; tl++) {
        bf16x8 w0 = *(const bf16x8*)(const void*)&wt1[(tl * 16 + l16) * 72 + q * 8];
        bf16x8 w1 = *(const bf16x8*)(const void*)&wt1[(tl * 16 + l16) * 72 + 32 + q * 8];
        f32x4 z = {0.f, 0.f, 0.f, 0.f};
        z = __builtin_amdgcn_mfma_f32_16x16x32_bf16(a0, w0, z, 0, 0, 0);
        z = __builtin_amdgcn_mfma_f32_16x16x32_bf16(a1, w1, z, 0, 0, 0);
        acc1[tl] = z;
    }
    // bias + LN(128) + relu
    float S[4] = {0, 0, 0, 0}, Q[4] = {0, 0, 0, 0};
#pragma unroll
    for (int tl = 0; tl < 8; tl++)
#pragma unroll
        for (int r = 0; r < 4; r++) {
            float v = acc1[tl][r] + b1v[tl];
            acc1[tl][r] = v;
            S[r] += v;
            Q[r] += v * v;
        }
#pragma unroll
    for (int m = 8; m >= 1; m >>= 1)
#pragma unroll
        for (int r = 0; r < 4; r++) {
            S[r] += __shfl_xor(S[r], m, 64);
            Q[r] += __shfl_xor(Q[r], m, 64);
        }
    float mu[4], rs[4];
#pragma unroll
    for (int r = 0; r < 4; r++) {
        mu[r] = S[r] * (1.f / 128.f);
        float var = Q[r] * (1.f / 128.f) - mu[r] * mu[r];
        rs[r] = rsqrtf(var + 1e-5f);
    }
#pragma unroll
    for (int tl = 0; tl < 8; tl++)
#pragma unroll
        for (int r = 0; r < 4; r++) {
            float h = fmaxf((acc1[tl][r] - mu[r]) * rs[r] * g1v[tl] + bev[tl], 0.f);
            hbuf[(wid * 16 + q * 4 + r) * 136 + tl * 16 + l16] = f2bf(h);
        }
    // wave-private LDS region: compiler orders via lgkmcnt, no barrier needed

    // GEMM2: [16x128] @ [128x64]
    bf16x8 a2[4];
#pragma unroll
    for (int c = 0; c < 4; c++)
        a2[c] = *(const bf16x8*)(const void*)&hbuf[(wid * 16 + l16) * 136 + c * 32 + q * 8];
    f32x4 acc2[4];
#pragma unroll
    for (int u = 0; u < 4; u++) {
        f32x4 z = {0.f, 0.f, 0.f, 0.f};
#pragma unroll
        for (int c = 0; c < 4; c++) {
            bf16x8 wf = *(const bf16x8*)(const void*)&wt2[(u * 16 + l16) * 136 + c * 32 + q * 8];
            z = __builtin_amdgcn_mfma_f32_16x16x32_bf16(a2[c], wf, z, 0, 0, 0);
        }
        acc2[u] = z;
    }
#pragma unroll
    for (int u = 0; u < 4; u++) {
        int col = u * 16 + l16;
        float bc = B2[col];
#pragma unroll
        for (int r = 0; r < 4; r++) {
            int node = m0 + q * 4 + r;
            if (node < NN) {
                float val = acc2[u][r] + bc;
                if (OUTfp) OUTfp[(size_t)node * HD + col] = val;
                OUTbf[(size_t)node * HD + col] = (u16)f2bf(val);
            }
        }
    }
}

// ---------------- fused tail ----------------
__global__ __launch_bounds__(256) void k_final(const float* __restrict__ X1,
                                               const u16* __restrict__ H2bf,
                                               const float* __restrict__ LG,
                                               const float* __restrict__ LB,
                                               const float* __restrict__ NG,
                                               const float* __restrict__ NB_,
                                               const float* __restrict__ LW,
                                               const float* __restrict__ LBias,
                                               float* __restrict__ out) {
    int t = threadIdx.x;
    int lane = t & 63, wid = t >> 6;
    int n = blockIdx.x * 4 + wid;
    if (n >= NN) return;
    float x1v = X1[(size_t)n * HD + lane];
    float h2v = bf2f(H2bf[(size_t)n * HD + lane]);
    float s = wredsum(h2v);
    float qq = wredsum(h2v * h2v);
    float mu = s * (1.f / 64.f);
    float var = qq * (1.f / 64.f) - mu * mu;
    float hn = fmaxf((h2v - mu) * rsqrtf(var + 1e-5f) * LG[lane] + LB[lane], 0.f);
    float s2 = wredsum(x1v + hn);
    float q2 = wredsum(x1v * x1v + hn * hn);
    float mu2 = s2 * (1.f / 128.f);
    float var2 = q2 * (1.f / 128.f) - mu2 * mu2;
    float rs2 = rsqrtf(var2 + 1e-5f);
    float av = fmaxf((x1v - mu2) * rs2 * NG[lane] + NB_[lane], 0.f);
    float bv = fmaxf((hn - mu2) * rs2 * NG[64 + lane] + NB_[64 + lane], 0.f);
    float acc = av * LW[lane] + bv * LW[64 + lane];
    float tot = wredsum(acc);
    if (lane == 0) out[n] = tot + LBias[0];
}

extern "C" void kernel_launch(void* const* d_in, const int* in_sizes, int n_in,
                              void* d_out, int out_size, void* d_ws, size_t ws_size,
                              hipStream_t stream) {
    const float* x = (const float*)d_in[0];
    const int* ei = (const int*)d_in[1];
    const float* encW = (const float*)d_in[2];
    const float* encB = (const float*)d_in[3];
    const float* tptr = (const float*)d_in[4];
    const float* cW1 = (const float*)d_in[5];
    const float* cB1 = (const float*)d_in[6];
    const float* cG1 = (const float*)d_in[7];
    const float* cBE1 = (const float*)d_in[8];
    const float* cW2 = (const float*)d_in[9];
    const float* cB2 = (const float*)d_in[10];
    const float* ln1g = (const float*)d_in[11];
    const float* ln1b = (const float*)d_in[12];
    const float* ng = (const float*)d_in[13];
    const float* nb = (const float*)d_in[14];
    const float* lw = (const float*)d_in[15];
    const float* lb = (const float*)d_in[16];

    char* w = (char*)d_ws;
    size_t off = 0;
    auto carve = [&](size_t bytes) {
        void* p = w + off;
        off += (bytes + 255) & ~(size_t)255;
        return p;
    };
    int* flag = (int*)carve(4);
    int* rowptr = (int*)carve((NN + 1) * 4);
    int* cnt = (int*)carve((size_t)NN * 4);
    int* bsum = (int*)carve(NB * 4);
    int* eSrc = (int*)carve((size_t)EE * 4);
    u16* Abf = (u16*)carve((size_t)NN * HD * 2);
    u16* AGbf = (u16*)carve((size_t)NN * HD * 2);
    float* X1 = (float*)carve((size_t)NN * HD * 4);
    u16* X1bf = (u16*)carve((size_t)NN * HD * 2);
    u16* H2bf = Abf;  // Abf dead after agg1

    hipMemsetAsync(flag, 0, 4, stream);
    hipMemsetAsync(cnt, 0, (size_t)NN * 4, stream);
    k_detect<<<4, 256, 0, stream>>>(ei, flag);
    k_hist<<<(EE + 255) / 256, 256, 0, stream>>>(ei, flag, cnt);
    k_scan1<<<NB, 256, 0, stream>>>(cnt, rowptr, bsum);
    k_scan2<<<1, 256, 0, stream>>>(bsum);
    k_scan3<<<NB, 256, 0, stream>>>(bsum, rowptr, cnt);  // also zeroes cnt
    k_scatter<<<(EE + 255) / 256, 256, 0, stream>>>(ei, flag, rowptr, cnt, eSrc);

    const int GB = (NN + 63) / 64;  // 782
    k_enc<<<GB, 256, 0, stream>>>(x, encW, encB, Abf);

    // conv1
    k_agg<<<2048, 256, 0, stream>>>(Abf, nullptr, rowptr, eSrc, tptr, AGbf);
    k_mlp<<<GB, 256, 0, stream>>>(AGbf, cW1, cB1, cG1, cBE1, cW2, cB2, X1, X1bf);
    // conv2 (shared weights)
    k_agg<<<2048, 256, 0, stream>>>(X1bf, X1, rowptr, eSrc, tptr, AGbf);
    k_mlp<<<GB, 256, 0, stream>>>(AGbf, cW1, cB1, cG1, cBE1, cW2, cB2, nullptr, H2bf);

    k_final<<<(NN + 3) / 4, 256, 0, stream>>>(X1, H2bf, ln1g, ln1b, ng, nb, lw, lb,
                                              (float*)d_out);
}